// Round 1
// baseline (2018.568 us; speedup 1.0000x reference)
//
#include <hip/hip_runtime.h>

#define N_NODES 100000
#define N_EDGES 1600000
#define IN_DIM 500
#define HID 32
#define N_REL 7
#define OUT_DIM 4
#define N_GRAPHS 16
#define NC 256   // (N_REL + 1) * HID: [root | rel0..rel6]

// ---------------- build Wcat [IN_DIM][NC] ----------------
__global__ void build_wcat(const float* __restrict__ W_root,
                           const float* __restrict__ W_rel,
                           float* __restrict__ Wcat) {
    int idx = blockIdx.x * blockDim.x + threadIdx.x;
    if (idx >= IN_DIM * NC) return;
    int c = idx & (NC - 1);
    int k = idx >> 8;
    float v;
    if (c < HID) {
        v = W_root[k * HID + c];
    } else {
        int r = (c >> 5) - 1;
        v = W_rel[((size_t)r * IN_DIM + k) * HID + (c & 31)];
    }
    Wcat[idx] = v;
}

// ---------------- GEMM: H[N_NODES, 256] = A[N_NODES,500] @ Wcat[500,256] ----
#define BM 64
#define KC 16
__global__ __launch_bounds__(256) void gemm_kernel(const float* __restrict__ A,
                                                   const float* __restrict__ B,
                                                   float* __restrict__ H) {
    __shared__ float As[KC][BM + 4];   // transposed: As[k][row]
    __shared__ float Bs[KC][NC];

    const int tid = threadIdx.x;
    const int row0 = blockIdx.x * BM;

    // compute mapping: thread -> 4 rows x 16 cols (cols spread by 64 to avoid bank conflicts)
    const int ty4 = (tid >> 4) * 4;   // row offset 0..60
    const int tx4 = (tid & 15) * 4;   // col offset 0..60 (plus j*64)

    // A staging mapping: each thread loads one float4 along k
    const int ar = tid >> 2;          // 0..63 row in tile
    const int ak = (tid & 3) * 4;     // 0,4,8,12 k offset

    // B staging mapping
    const int b_kk = tid >> 4;        // 0..15
    const int b_c = (tid & 15) * 4;   // 0..60

    float acc[4][4][4];
    #pragma unroll
    for (int i = 0; i < 4; i++)
        #pragma unroll
        for (int j = 0; j < 4; j++)
            #pragma unroll
            for (int jj = 0; jj < 4; jj++) acc[i][j][jj] = 0.f;

    for (int k0 = 0; k0 < IN_DIM; k0 += KC) {
        // ---- stage A (64 rows x 16 k), transposed into LDS ----
        {
            int ka = k0 + ak;
            int grow = row0 + ar;
            float4 av4 = make_float4(0.f, 0.f, 0.f, 0.f);
            if (grow < N_NODES && ka < IN_DIM)   // IN_DIM%4==0 -> whole float4 valid
                av4 = *(const float4*)(A + (size_t)grow * IN_DIM + ka);
            As[ak + 0][ar] = av4.x;
            As[ak + 1][ar] = av4.y;
            As[ak + 2][ar] = av4.z;
            As[ak + 3][ar] = av4.w;
        }
        // ---- stage B (16 k x 256 cols) ----
        {
            int kb = k0 + b_kk;
            #pragma unroll
            for (int j = 0; j < 4; j++) {
                float4 v = make_float4(0.f, 0.f, 0.f, 0.f);
                if (kb < IN_DIM)
                    v = *(const float4*)(B + (size_t)kb * NC + j * 64 + b_c);
                *(float4*)(&Bs[b_kk][j * 64 + b_c]) = v;
            }
        }
        __syncthreads();

        #pragma unroll
        for (int kk = 0; kk < KC; kk++) {
            float4 a = *(const float4*)(&As[kk][ty4]);
            float av[4] = {a.x, a.y, a.z, a.w};
            float bv[4][4];
            #pragma unroll
            for (int j = 0; j < 4; j++) {
                float4 b = *(const float4*)(&Bs[kk][j * 64 + tx4]);
                bv[j][0] = b.x; bv[j][1] = b.y; bv[j][2] = b.z; bv[j][3] = b.w;
            }
            #pragma unroll
            for (int i = 0; i < 4; i++)
                #pragma unroll
                for (int j = 0; j < 4; j++)
                    #pragma unroll
                    for (int jj = 0; jj < 4; jj++)
                        acc[i][j][jj] = fmaf(av[i], bv[j][jj], acc[i][j][jj]);
        }
        __syncthreads();
    }

    #pragma unroll
    for (int i = 0; i < 4; i++) {
        int r = row0 + ty4 + i;
        if (r < N_NODES) {
            #pragma unroll
            for (int j = 0; j < 4; j++) {
                float4 o = make_float4(acc[i][j][0], acc[i][j][1], acc[i][j][2], acc[i][j][3]);
                *(float4*)(H + (size_t)r * NC + j * 64 + tx4) = o;
            }
        }
    }
}

// ---------------- edge degree count per (dst, rel) ----------------
__global__ void count_edges(const int* __restrict__ dst, const int* __restrict__ attr,
                            int* __restrict__ cnt) {
    int e = blockIdx.x * blockDim.x + threadIdx.x;
    if (e >= N_EDGES) return;
    atomicAdd(&cnt[dst[e] * N_REL + attr[e]], 1);
}

// in-place int count -> float 1/max(cnt,1)
__global__ void make_invcnt(int* __restrict__ p) {
    int i = blockIdx.x * blockDim.x + threadIdx.x;
    if (i >= N_NODES * N_REL) return;
    int c = p[i];
    float v = 1.0f / (float)(c > 1 ? c : 1);
    p[i] = __float_as_int(v);
}

// ---------------- edge aggregation: nodeacc[dst] += H[src, rel] * invcnt ----
__global__ void edge_agg(const int* __restrict__ src, const int* __restrict__ dst,
                         const int* __restrict__ attr, const float* __restrict__ H,
                         const float* __restrict__ invcnt, float* __restrict__ nodeacc) {
    int t = blockIdx.x * blockDim.x + threadIdx.x;
    int e = t >> 2;
    if (e >= N_EDGES) return;
    int part = t & 3;                       // 8 cols each
    int s = src[e];
    int d = dst[e];
    int r = attr[e];
    float w = invcnt[d * N_REL + r];
    const float4* hp = (const float4*)(H + (size_t)s * NC + (r + 1) * HID + part * 8);
    float4 h0 = hp[0];
    float4 h1 = hp[1];
    float* op = nodeacc + (size_t)d * HID + part * 8;
    atomicAdd(op + 0, h0.x * w);
    atomicAdd(op + 1, h0.y * w);
    atomicAdd(op + 2, h0.z * w);
    atomicAdd(op + 3, h0.w * w);
    atomicAdd(op + 4, h1.x * w);
    atomicAdd(op + 5, h1.y * w);
    atomicAdd(op + 6, h1.z * w);
    atomicAdd(op + 7, h1.w * w);
}

// ---------------- relu + pool ----------------
__global__ __launch_bounds__(256) void pool_kernel(const float* __restrict__ H,
                                                   const float* __restrict__ nodeacc,
                                                   const float* __restrict__ bias,
                                                   const int* __restrict__ batch,
                                                   float* __restrict__ pooled) {
    __shared__ float lpool[N_GRAPHS][HID + 1];
    int t = threadIdx.x;
    for (int i = t; i < N_GRAPHS * (HID + 1); i += 256) ((float*)lpool)[i] = 0.f;
    __syncthreads();

    int c = t & 31;
    int nl = t >> 5;  // 0..7
    float b = bias[c];
    int n0 = blockIdx.x * 256;
    for (int it = 0; it < 32; it++) {
        int n = n0 + it * 8 + nl;
        if (n < N_NODES) {
            float v = H[(size_t)n * NC + c] + b + nodeacc[(size_t)n * HID + c];
            v = fmaxf(v, 0.f);
            int g = batch[n];
            atomicAdd(&lpool[g][c], v);
        }
    }
    __syncthreads();
    for (int i = t; i < N_GRAPHS * HID; i += 256) {
        int g = i >> 5, c2 = i & 31;
        float v = lpool[g][c2];
        if (v != 0.f) atomicAdd(&pooled[g * HID + c2], v);
    }
}

// ---------------- final FC: out[16,4] = pooled[16,32] @ fc_w + fc_b ----------
__global__ void fc_kernel(const float* __restrict__ pooled, const float* __restrict__ fc_w,
                          const float* __restrict__ fc_b, float* __restrict__ out) {
    int t = threadIdx.x;
    if (t >= N_GRAPHS * OUT_DIM) return;
    int g = t >> 2, o = t & 3;
    float acc = fc_b[o];
    #pragma unroll
    for (int c = 0; c < HID; c++) acc += pooled[g * HID + c] * fc_w[c * OUT_DIM + o];
    out[t] = acc;
}

extern "C" void kernel_launch(void* const* d_in, const int* in_sizes, int n_in,
                              void* d_out, int out_size, void* d_ws, size_t ws_size,
                              hipStream_t stream) {
    const float* node_x  = (const float*)d_in[0];
    const int*   edge_ix = (const int*)d_in[1];
    const int*   e_attr  = (const int*)d_in[2];
    const int*   batch   = (const int*)d_in[3];
    const float* W_rel   = (const float*)d_in[4];
    const float* W_root  = (const float*)d_in[5];
    const float* bias    = (const float*)d_in[6];
    const float* fc_w    = (const float*)d_in[7];
    const float* fc_b    = (const float*)d_in[8];
    float* out = (float*)d_out;

    char* ws = (char*)d_ws;
    size_t off = 0;
    auto alloc = [&](size_t bytes) {
        char* p = ws + off;
        off += (bytes + 255) & ~(size_t)255;
        return p;
    };
    float* Wcat    = (float*)alloc((size_t)IN_DIM * NC * 4);        // 512 KB
    float* H       = (float*)alloc((size_t)N_NODES * NC * 4);       // 102.4 MB
    float* nodeacc = (float*)alloc((size_t)N_NODES * HID * 4);      // 12.8 MB
    int*   cnt     = (int*)  alloc((size_t)N_NODES * N_REL * 4);    // 2.8 MB
    float* pooled  = (float*)alloc((size_t)N_GRAPHS * HID * 4);     // 2 KB
    (void)ws_size; (void)in_sizes; (void)n_in; (void)out_size;

    const int* src = edge_ix;
    const int* dst = edge_ix + N_EDGES;

    hipMemsetAsync(nodeacc, 0, (size_t)N_NODES * HID * 4, stream);
    hipMemsetAsync(cnt, 0, (size_t)N_NODES * N_REL * 4, stream);
    hipMemsetAsync(pooled, 0, (size_t)N_GRAPHS * HID * 4, stream);

    build_wcat<<<(IN_DIM * NC + 255) / 256, 256, 0, stream>>>(W_root, W_rel, Wcat);

    gemm_kernel<<<(N_NODES + BM - 1) / BM, 256, 0, stream>>>(node_x, Wcat, H);

    count_edges<<<(N_EDGES + 255) / 256, 256, 0, stream>>>(dst, e_attr, cnt);
    make_invcnt<<<(N_NODES * N_REL + 255) / 256, 256, 0, stream>>>(cnt);

    edge_agg<<<((N_EDGES * 4) + 255) / 256, 256, 0, stream>>>(src, dst, e_attr, H,
                                                              (const float*)cnt, nodeacc);

    pool_kernel<<<(N_NODES + 255) / 256, 256, 0, stream>>>(H, nodeacc, bias, batch, pooled);

    fc_kernel<<<1, 64, 0, stream>>>(pooled, fc_w, fc_b, out);
}

// Round 2
// 936.344 us; speedup vs baseline: 2.1558x; 2.1558x over previous
//
#include <hip/hip_runtime.h>

#define N_NODES 100000
#define N_EDGES 1600000
#define IN_DIM 500
#define HID 32
#define N_REL 7
#define OUT_DIM 4
#define N_GRAPHS 16
#define NC 256   // (N_REL + 1) * HID: [root | rel0..rel6]

#define SCAN_ITEMS 1024
#define SCAN_BLOCKS ((N_NODES + SCAN_ITEMS - 1) / SCAN_ITEMS)   // 98

// ---------------- build Wcat [IN_DIM][NC] ----------------
__global__ void build_wcat(const float* __restrict__ W_root,
                           const float* __restrict__ W_rel,
                           float* __restrict__ Wcat) {
    int idx = blockIdx.x * blockDim.x + threadIdx.x;
    if (idx >= IN_DIM * NC) return;
    int c = idx & (NC - 1);
    int k = idx >> 8;
    float v;
    if (c < HID) {
        v = W_root[k * HID + c];
    } else {
        int r = (c >> 5) - 1;
        v = W_rel[((size_t)r * IN_DIM + k) * HID + (c & 31)];
    }
    Wcat[idx] = v;
}

// ---------------- GEMM: H[N_NODES, 256] = A[N_NODES,500] @ Wcat[500,256] ----
#define BM 64
#define KC 16
__global__ __launch_bounds__(256) void gemm_kernel(const float* __restrict__ A,
                                                   const float* __restrict__ B,
                                                   float* __restrict__ H) {
    __shared__ float As[KC][BM + 4];   // transposed: As[k][row]
    __shared__ float Bs[KC][NC];

    const int tid = threadIdx.x;
    const int row0 = blockIdx.x * BM;

    const int ty4 = (tid >> 4) * 4;   // row offset 0..60
    const int tx4 = (tid & 15) * 4;   // col offset 0..60 (plus j*64)

    const int ar = tid >> 2;          // 0..63 row in tile
    const int ak = (tid & 3) * 4;     // 0,4,8,12 k offset

    const int b_kk = tid >> 4;        // 0..15
    const int b_c = (tid & 15) * 4;   // 0..60

    float acc[4][4][4];
    #pragma unroll
    for (int i = 0; i < 4; i++)
        #pragma unroll
        for (int j = 0; j < 4; j++)
            #pragma unroll
            for (int jj = 0; jj < 4; jj++) acc[i][j][jj] = 0.f;

    for (int k0 = 0; k0 < IN_DIM; k0 += KC) {
        {
            int ka = k0 + ak;
            int grow = row0 + ar;
            float4 av4 = make_float4(0.f, 0.f, 0.f, 0.f);
            if (grow < N_NODES && ka < IN_DIM)
                av4 = *(const float4*)(A + (size_t)grow * IN_DIM + ka);
            As[ak + 0][ar] = av4.x;
            As[ak + 1][ar] = av4.y;
            As[ak + 2][ar] = av4.z;
            As[ak + 3][ar] = av4.w;
        }
        {
            int kb = k0 + b_kk;
            #pragma unroll
            for (int j = 0; j < 4; j++) {
                float4 v = make_float4(0.f, 0.f, 0.f, 0.f);
                if (kb < IN_DIM)
                    v = *(const float4*)(B + (size_t)kb * NC + j * 64 + b_c);
                *(float4*)(&Bs[b_kk][j * 64 + b_c]) = v;
            }
        }
        __syncthreads();

        #pragma unroll
        for (int kk = 0; kk < KC; kk++) {
            float4 a = *(const float4*)(&As[kk][ty4]);
            float av[4] = {a.x, a.y, a.z, a.w};
            float bv[4][4];
            #pragma unroll
            for (int j = 0; j < 4; j++) {
                float4 b = *(const float4*)(&Bs[kk][j * 64 + tx4]);
                bv[j][0] = b.x; bv[j][1] = b.y; bv[j][2] = b.z; bv[j][3] = b.w;
            }
            #pragma unroll
            for (int i = 0; i < 4; i++)
                #pragma unroll
                for (int j = 0; j < 4; j++)
                    #pragma unroll
                    for (int jj = 0; jj < 4; jj++)
                        acc[i][j][jj] = fmaf(av[i], bv[j][jj], acc[i][j][jj]);
        }
        __syncthreads();
    }

    #pragma unroll
    for (int i = 0; i < 4; i++) {
        int r = row0 + ty4 + i;
        if (r < N_NODES) {
            #pragma unroll
            for (int j = 0; j < 4; j++) {
                float4 o = make_float4(acc[i][j][0], acc[i][j][1], acc[i][j][2], acc[i][j][3]);
                *(float4*)(H + (size_t)r * NC + j * 64 + tx4) = o;
            }
        }
    }
}

// ---------------- edge degree count per (dst, rel) ----------------
__global__ void count_edges(const int* __restrict__ dst, const int* __restrict__ attr,
                            int* __restrict__ cnt) {
    int e = blockIdx.x * blockDim.x + threadIdx.x;
    if (e >= N_EDGES) return;
    atomicAdd(&cnt[dst[e] * N_REL + attr[e]], 1);
}

// per node: deg[d] = sum_r cnt; cnt -> float 1/max(cnt,1) in place
__global__ void make_invcnt_deg(int* __restrict__ cnt, int* __restrict__ deg) {
    int d = blockIdx.x * blockDim.x + threadIdx.x;
    if (d >= N_NODES) return;
    int total = 0;
    #pragma unroll
    for (int r = 0; r < N_REL; r++) {
        int c = cnt[d * N_REL + r];
        total += c;
        float v = 1.0f / (float)(c > 1 ? c : 1);
        cnt[d * N_REL + r] = __float_as_int(v);
    }
    deg[d] = total;
}

// ---------------- exclusive scan of deg -> offsets (3 phases) ----------------
__global__ __launch_bounds__(256) void scan1(const int* __restrict__ deg,
                                             int* __restrict__ offs,
                                             int* __restrict__ bsums) {
    __shared__ int ss[256];
    int t = threadIdx.x;
    int base = blockIdx.x * SCAN_ITEMS + t * 4;
    int v[4];
    #pragma unroll
    for (int j = 0; j < 4; j++) {
        int idx = base + j;
        v[j] = idx < N_NODES ? deg[idx] : 0;
    }
    int tsum = v[0] + v[1] + v[2] + v[3];
    ss[t] = tsum;
    __syncthreads();
    for (int off = 1; off < 256; off <<= 1) {
        int x = (t >= off) ? ss[t - off] : 0;
        __syncthreads();
        ss[t] += x;
        __syncthreads();
    }
    int excl = ss[t] - tsum;   // exclusive prefix of this thread within block
    if (t == 255) bsums[blockIdx.x] = ss[255];
    int run = excl;
    #pragma unroll
    for (int j = 0; j < 4; j++) {
        int idx = base + j;
        if (idx < N_NODES) offs[idx] = run;
        run += v[j];
    }
}

__global__ void scan2(int* __restrict__ bsums) {
    if (threadIdx.x == 0 && blockIdx.x == 0) {
        int run = 0;
        for (int i = 0; i < SCAN_BLOCKS; i++) {
            int v = bsums[i];
            bsums[i] = run;
            run += v;
        }
    }
}

// offs += bsums[block]; cursor = offs
__global__ void scan3(int* __restrict__ offs, const int* __restrict__ bsums,
                      int* __restrict__ cursor) {
    int i = blockIdx.x * blockDim.x + threadIdx.x;
    if (i >= N_NODES) return;
    int v = offs[i] + bsums[i >> 10];
    offs[i] = v;
    cursor[i] = v;
}

// ---------------- build permutation (dst-sorted edge ids) ----------------
__global__ void perm_build(const int* __restrict__ dst, int* __restrict__ cursor,
                           int* __restrict__ perm) {
    int e = blockIdx.x * blockDim.x + threadIdx.x;
    if (e >= N_EDGES) return;
    int p = atomicAdd(&cursor[dst[e]], 1);
    perm[p] = e;
}

// ---------------- gather aggregation: one wave per dst node ----------------
// result (root + bias + sum_r mean_r, relu'd) written IN PLACE into H[d*NC + c]
__global__ __launch_bounds__(256) void gather_agg(const int* __restrict__ src,
                                                  const int* __restrict__ attr,
                                                  const int* __restrict__ perm,
                                                  const int* __restrict__ cursor,
                                                  const int* __restrict__ deg,
                                                  const float* __restrict__ invcnt,
                                                  const float* __restrict__ bias,
                                                  float* __restrict__ H) {
    int wave = threadIdx.x >> 6;
    int lane = threadIdx.x & 63;
    int d = blockIdx.x * 4 + wave;
    if (d >= N_NODES) return;
    int c = lane & 31;
    int half = lane >> 5;

    int dg = deg[d];
    int end = cursor[d];          // after perm_build, cursor[d] == offs[d] + deg[d]
    int start = end - dg;

    float acc = 0.f;
    for (int i = start + half; i < end; i += 2) {
        int e = perm[i];
        int s = src[e];
        int r = attr[e];
        float w = invcnt[d * N_REL + r];
        acc += H[(size_t)s * NC + (r + 1) * HID + c] * w;
    }
    acc += __shfl_down(acc, 32);

    if (half == 0) {
        float v = H[(size_t)d * NC + c] + bias[c] + acc;
        H[(size_t)d * NC + c] = fmaxf(v, 0.f);
    }
}

// ---------------- pool (reads relu'd node values from H root slot) ----------
__global__ __launch_bounds__(256) void pool_kernel(const float* __restrict__ H,
                                                   const int* __restrict__ batch,
                                                   float* __restrict__ pooled) {
    __shared__ float lpool[N_GRAPHS][HID + 1];
    int t = threadIdx.x;
    for (int i = t; i < N_GRAPHS * (HID + 1); i += 256) ((float*)lpool)[i] = 0.f;
    __syncthreads();

    int c = t & 31;
    int nl = t >> 5;  // 0..7
    int n0 = blockIdx.x * 256;
    for (int it = 0; it < 32; it++) {
        int n = n0 + it * 8 + nl;
        if (n < N_NODES) {
            float v = H[(size_t)n * NC + c];
            int g = batch[n];
            atomicAdd(&lpool[g][c], v);
        }
    }
    __syncthreads();
    for (int i = t; i < N_GRAPHS * HID; i += 256) {
        int g = i >> 5, c2 = i & 31;
        float v = lpool[g][c2];
        if (v != 0.f) atomicAdd(&pooled[g * HID + c2], v);
    }
}

// ---------------- final FC: out[16,4] = pooled[16,32] @ fc_w + fc_b ----------
__global__ void fc_kernel(const float* __restrict__ pooled, const float* __restrict__ fc_w,
                          const float* __restrict__ fc_b, float* __restrict__ out) {
    int t = threadIdx.x;
    if (t >= N_GRAPHS * OUT_DIM) return;
    int g = t >> 2, o = t & 3;
    float acc = fc_b[o];
    #pragma unroll
    for (int c = 0; c < HID; c++) acc += pooled[g * HID + c] * fc_w[c * OUT_DIM + o];
    out[t] = acc;
}

extern "C" void kernel_launch(void* const* d_in, const int* in_sizes, int n_in,
                              void* d_out, int out_size, void* d_ws, size_t ws_size,
                              hipStream_t stream) {
    const float* node_x  = (const float*)d_in[0];
    const int*   edge_ix = (const int*)d_in[1];
    const int*   e_attr  = (const int*)d_in[2];
    const int*   batch   = (const int*)d_in[3];
    const float* W_rel   = (const float*)d_in[4];
    const float* W_root  = (const float*)d_in[5];
    const float* bias    = (const float*)d_in[6];
    const float* fc_w    = (const float*)d_in[7];
    const float* fc_b    = (const float*)d_in[8];
    float* out = (float*)d_out;

    char* ws = (char*)d_ws;
    size_t off = 0;
    auto alloc = [&](size_t bytes) {
        char* p = ws + off;
        off += (bytes + 255) & ~(size_t)255;
        return p;
    };
    float* Wcat    = (float*)alloc((size_t)IN_DIM * NC * 4);        // 512 KB
    float* H       = (float*)alloc((size_t)N_NODES * NC * 4);       // 102.4 MB
    int*   cnt     = (int*)  alloc((size_t)N_NODES * N_REL * 4);    // 2.8 MB (becomes invcnt)
    int*   deg     = (int*)  alloc((size_t)N_NODES * 4);            // 0.4 MB
    int*   offs    = (int*)  alloc((size_t)N_NODES * 4);            // 0.4 MB
    int*   cursor  = (int*)  alloc((size_t)N_NODES * 4);            // 0.4 MB
    int*   perm    = (int*)  alloc((size_t)N_EDGES * 4);            // 6.4 MB
    int*   bsums   = (int*)  alloc((size_t)SCAN_BLOCKS * 4);
    float* pooled  = (float*)alloc((size_t)N_GRAPHS * HID * 4);     // 2 KB
    (void)ws_size; (void)in_sizes; (void)n_in; (void)out_size;

    const int* src = edge_ix;
    const int* dst = edge_ix + N_EDGES;

    hipMemsetAsync(cnt, 0, (size_t)N_NODES * N_REL * 4, stream);
    hipMemsetAsync(pooled, 0, (size_t)N_GRAPHS * HID * 4, stream);

    build_wcat<<<(IN_DIM * NC + 255) / 256, 256, 0, stream>>>(W_root, W_rel, Wcat);

    gemm_kernel<<<(N_NODES + BM - 1) / BM, 256, 0, stream>>>(node_x, Wcat, H);

    count_edges<<<(N_EDGES + 255) / 256, 256, 0, stream>>>(dst, e_attr, cnt);
    make_invcnt_deg<<<(N_NODES + 255) / 256, 256, 0, stream>>>(cnt, deg);

    scan1<<<SCAN_BLOCKS, 256, 0, stream>>>(deg, offs, bsums);
    scan2<<<1, 64, 0, stream>>>(bsums);
    scan3<<<(N_NODES + 255) / 256, 256, 0, stream>>>(offs, bsums, cursor);

    perm_build<<<(N_EDGES + 255) / 256, 256, 0, stream>>>(dst, cursor, perm);

    gather_agg<<<(N_NODES + 3) / 4, 256, 0, stream>>>(src, e_attr, perm, cursor, deg,
                                                      (const float*)cnt, bias, H);

    pool_kernel<<<(N_NODES + 255) / 256, 256, 0, stream>>>(H, batch, pooled);

    fc_kernel<<<1, 64, 0, stream>>>(pooled, fc_w, fc_b, out);
}

// Round 3
// 744.811 us; speedup vs baseline: 2.7102x; 1.2572x over previous
//
#include <hip/hip_runtime.h>

#define N_NODES 100000
#define N_EDGES 1600000
#define IN_DIM 500
#define HID 32
#define N_REL 7
#define OUT_DIM 4
#define N_GRAPHS 16
#define NC 256   // (N_REL + 1) * HID: [root | rel0..rel6]
#define KPAD 512
#define KSTEPS 16

#define SCAN_ITEMS 1024
#define SCAN_BLOCKS ((N_NODES + SCAN_ITEMS - 1) / SCAN_ITEMS)   // 98

typedef __attribute__((ext_vector_type(8))) short bf16x8;
typedef __attribute__((ext_vector_type(4))) float f32x4;

__device__ inline unsigned short f2bf(float f) {
    unsigned u = __float_as_uint(f);
    unsigned r = (u + 0x7FFFu + ((u >> 16) & 1u)) >> 16;
    return (unsigned short)r;
}

__device__ inline uint4 cvt8(float4 a, float4 b) {
    uint4 r;
    r.x = (unsigned)f2bf(a.x) | ((unsigned)f2bf(a.y) << 16);
    r.y = (unsigned)f2bf(a.z) | ((unsigned)f2bf(a.w) << 16);
    r.z = (unsigned)f2bf(b.x) | ((unsigned)f2bf(b.y) << 16);
    r.w = (unsigned)f2bf(b.z) | ((unsigned)f2bf(b.w) << 16);
    return r;
}

// ---------------- build Wbf: bf16 B-matrix in MFMA fragment order ----------
// layout: [ks][q][n 0..255][j], element k = ks*32 + q*8 + j (zero for k>=500)
__global__ void build_wbf(const float* __restrict__ W_root,
                          const float* __restrict__ W_rel,
                          unsigned short* __restrict__ Wbf) {
    int idx = blockIdx.x * blockDim.x + threadIdx.x;   // 0 .. KPAD*NC-1
    if (idx >= KPAD * NC) return;
    int kk = idx >> 8;
    int n = idx & 255;
    float v = 0.f;
    if (kk < IN_DIM) {
        if (n < HID) v = W_root[kk * HID + n];
        else {
            int r = (n >> 5) - 1;
            v = W_rel[((size_t)r * IN_DIM + kk) * HID + (n & 31)];
        }
    }
    int ks = kk >> 5, q = (kk >> 3) & 3, j = kk & 7;
    Wbf[(size_t)((((ks << 2) + q) << 8) + n) * 8 + j] = f2bf(v);
}

// ---------------- MFMA GEMM: H[N,256] = bf16(A[N,500]) @ Wbf --------------
// block: 256 threads (4 waves), tile 128 rows x 128 cols (2 col-halves)
__global__ __launch_bounds__(256) void gemm_mfma(const float* __restrict__ A,
                                                 const uint4* __restrict__ Wbf,
                                                 float* __restrict__ H) {
    // A LDS: [q][m 0..127][8 bf16], q-stride padded 128->132 to break write conflicts
    __shared__ uint4 Alds[4 * 132];
    __shared__ uint4 Blds[4 * 128];

    const int tid = threadIdx.x;
    const int wave = tid >> 6, lane = tid & 63;
    const int bm = blockIdx.x >> 1, ch = blockIdx.x & 1;
    const int row0 = bm * 128;
    const int wm = (wave >> 1) * 64, wn = (wave & 1) * 64;
    const int l16 = lane & 15, q = lane >> 4;

    // A staging map: thread -> (arow, akq) and (arow+64, akq)
    const int arow = tid >> 2;
    const int akq = tid & 3;
    const bool v0 = (row0 + arow) < N_NODES;
    const bool v1 = (row0 + arow + 64) < N_NODES;
    const float* Ap0 = A + (size_t)(row0 + arow) * IN_DIM + akq * 8;
    const float* Ap1 = A + (size_t)(row0 + arow + 64) * IN_DIM + akq * 8;

    // B staging map
    const int bq = tid >> 7;       // 0..1 (and +2)
    const int bn = tid & 127;

    f32x4 acc[4][4];
    #pragma unroll
    for (int mt = 0; mt < 4; mt++)
        #pragma unroll
        for (int nt = 0; nt < 4; nt++)
            #pragma unroll
            for (int r = 0; r < 4; r++) acc[mt][nt][r] = 0.f;

    for (int ks = 0; ks < KSTEPS; ks++) {
        const int k0 = ks * 32;
        // ---- stage A (fp32 -> bf16) ----
        if (ks < KSTEPS - 1) {
            float4 z = make_float4(0.f, 0.f, 0.f, 0.f);
            float4 a0 = v0 ? *(const float4*)(Ap0 + k0) : z;
            float4 a1 = v0 ? *(const float4*)(Ap0 + k0 + 4) : z;
            Alds[akq * 132 + arow] = cvt8(a0, a1);
            float4 b0 = v1 ? *(const float4*)(Ap1 + k0) : z;
            float4 b1 = v1 ? *(const float4*)(Ap1 + k0 + 4) : z;
            Alds[akq * 132 + arow + 64] = cvt8(b0, b1);
        } else {
            // boundary k-step: k in [480, 512), valid only k < 500
            float f0[8], f1[8];
            #pragma unroll
            for (int jj = 0; jj < 8; jj++) {
                int k = k0 + akq * 8 + jj;
                f0[jj] = (v0 && k < IN_DIM) ? A[(size_t)(row0 + arow) * IN_DIM + k] : 0.f;
                f1[jj] = (v1 && k < IN_DIM) ? A[(size_t)(row0 + arow + 64) * IN_DIM + k] : 0.f;
            }
            Alds[akq * 132 + arow] = cvt8(make_float4(f0[0], f0[1], f0[2], f0[3]),
                                          make_float4(f0[4], f0[5], f0[6], f0[7]));
            Alds[akq * 132 + arow + 64] = cvt8(make_float4(f1[0], f1[1], f1[2], f1[3]),
                                               make_float4(f1[4], f1[5], f1[6], f1[7]));
        }
        // ---- stage B (straight 16B copies, fragment-order global layout) ----
        Blds[bq * 128 + bn] = Wbf[(size_t)(ks * 4 + bq) * 256 + ch * 128 + bn];
        Blds[(bq + 2) * 128 + bn] = Wbf[(size_t)(ks * 4 + bq + 2) * 256 + ch * 128 + bn];
        __syncthreads();

        bf16x8 afr[4], bfr[4];
        #pragma unroll
        for (int mt = 0; mt < 4; mt++)
            afr[mt] = *(const bf16x8*)&Alds[q * 132 + wm + mt * 16 + l16];
        #pragma unroll
        for (int nt = 0; nt < 4; nt++)
            bfr[nt] = *(const bf16x8*)&Blds[q * 128 + wn + nt * 16 + l16];

        #pragma unroll
        for (int mt = 0; mt < 4; mt++)
            #pragma unroll
            for (int nt = 0; nt < 4; nt++)
                acc[mt][nt] = __builtin_amdgcn_mfma_f32_16x16x32_bf16(
                    afr[mt], bfr[nt], acc[mt][nt], 0, 0, 0);
        __syncthreads();
    }

    // ---- store: C/D layout col=lane&15, row=(lane>>4)*4+reg ----
    #pragma unroll
    for (int mt = 0; mt < 4; mt++) {
        int rbase = row0 + wm + mt * 16 + q * 4;
        #pragma unroll
        for (int r = 0; r < 4; r++) {
            int row = rbase + r;
            if (row < N_NODES) {
                float* hp = H + (size_t)row * NC + ch * 128 + wn + l16;
                #pragma unroll
                for (int nt = 0; nt < 4; nt++) hp[nt * 16] = acc[mt][nt][r];
            }
        }
    }
}

// ---------------- edge degree count per (dst, rel) ----------------
__global__ void count_edges(const int* __restrict__ dst, const int* __restrict__ attr,
                            int* __restrict__ cnt) {
    int e = blockIdx.x * blockDim.x + threadIdx.x;
    if (e >= N_EDGES) return;
    atomicAdd(&cnt[dst[e] * N_REL + attr[e]], 1);
}

// per node: deg[d] = sum_r cnt; cnt -> float 1/max(cnt,1) in place
__global__ void make_invcnt_deg(int* __restrict__ cnt, int* __restrict__ deg) {
    int d = blockIdx.x * blockDim.x + threadIdx.x;
    if (d >= N_NODES) return;
    int total = 0;
    #pragma unroll
    for (int r = 0; r < N_REL; r++) {
        int c = cnt[d * N_REL + r];
        total += c;
        float v = 1.0f / (float)(c > 1 ? c : 1);
        cnt[d * N_REL + r] = __float_as_int(v);
    }
    deg[d] = total;
}

// ---------------- exclusive scan of deg -> offsets ----------------
__global__ __launch_bounds__(256) void scan1(const int* __restrict__ deg,
                                             int* __restrict__ offs,
                                             int* __restrict__ bsums) {
    __shared__ int ss[256];
    int t = threadIdx.x;
    int base = blockIdx.x * SCAN_ITEMS + t * 4;
    int v[4];
    #pragma unroll
    for (int j = 0; j < 4; j++) {
        int idx = base + j;
        v[j] = idx < N_NODES ? deg[idx] : 0;
    }
    int tsum = v[0] + v[1] + v[2] + v[3];
    ss[t] = tsum;
    __syncthreads();
    for (int off = 1; off < 256; off <<= 1) {
        int x = (t >= off) ? ss[t - off] : 0;
        __syncthreads();
        ss[t] += x;
        __syncthreads();
    }
    int excl = ss[t] - tsum;
    if (t == 255) bsums[blockIdx.x] = ss[255];
    int run = excl;
    #pragma unroll
    for (int j = 0; j < 4; j++) {
        int idx = base + j;
        if (idx < N_NODES) offs[idx] = run;
        run += v[j];
    }
}

__global__ void scan2(int* __restrict__ bsums) {
    if (threadIdx.x == 0 && blockIdx.x == 0) {
        int run = 0;
        for (int i = 0; i < SCAN_BLOCKS; i++) {
            int v = bsums[i];
            bsums[i] = run;
            run += v;
        }
    }
}

__global__ void scan3(int* __restrict__ offs, const int* __restrict__ bsums,
                      int* __restrict__ cursor) {
    int i = blockIdx.x * blockDim.x + threadIdx.x;
    if (i >= N_NODES) return;
    int v = offs[i] + bsums[i >> 10];
    offs[i] = v;
    cursor[i] = v;
}

// ---------------- build permutation (dst-sorted edge ids) ----------------
__global__ void perm_build(const int* __restrict__ dst, int* __restrict__ cursor,
                           int* __restrict__ perm) {
    int e = blockIdx.x * blockDim.x + threadIdx.x;
    if (e >= N_EDGES) return;
    int p = atomicAdd(&cursor[dst[e]], 1);
    perm[p] = e;
}

// ---------------- gather aggregation: one wave per dst node ----------------
// 4x unrolled: 8 independent gather loads in flight per wave
__global__ __launch_bounds__(256) void gather_agg(const int* __restrict__ src,
                                                  const int* __restrict__ attr,
                                                  const int* __restrict__ perm,
                                                  const int* __restrict__ cursor,
                                                  const int* __restrict__ deg,
                                                  const float* __restrict__ invcnt,
                                                  const float* __restrict__ bias,
                                                  float* __restrict__ H) {
    int wave = threadIdx.x >> 6;
    int lane = threadIdx.x & 63;
    int d = blockIdx.x * 4 + wave;
    if (d >= N_NODES) return;
    int c = lane & 31;
    int half = lane >> 5;

    int dg = deg[d];
    int end = cursor[d];          // cursor[d] == offs[d] + deg[d] after perm_build
    int start = end - dg;

    float acc = 0.f;
    int i = start + half;
    for (; i + 6 < end; i += 8) {
        int e0 = perm[i];
        int e1 = perm[i + 2];
        int e2 = perm[i + 4];
        int e3 = perm[i + 6];
        int s0 = src[e0], s1 = src[e1], s2 = src[e2], s3 = src[e3];
        int r0 = attr[e0], r1 = attr[e1], r2 = attr[e2], r3 = attr[e3];
        float w0 = invcnt[d * N_REL + r0];
        float w1 = invcnt[d * N_REL + r1];
        float w2 = invcnt[d * N_REL + r2];
        float w3 = invcnt[d * N_REL + r3];
        float h0 = H[(size_t)s0 * NC + (r0 + 1) * HID + c];
        float h1 = H[(size_t)s1 * NC + (r1 + 1) * HID + c];
        float h2 = H[(size_t)s2 * NC + (r2 + 1) * HID + c];
        float h3 = H[(size_t)s3 * NC + (r3 + 1) * HID + c];
        acc = fmaf(h0, w0, acc);
        acc = fmaf(h1, w1, acc);
        acc = fmaf(h2, w2, acc);
        acc = fmaf(h3, w3, acc);
    }
    for (; i < end; i += 2) {
        int e = perm[i];
        int s = src[e];
        int r = attr[e];
        float w = invcnt[d * N_REL + r];
        acc = fmaf(H[(size_t)s * NC + (r + 1) * HID + c], w, acc);
    }
    acc += __shfl_down(acc, 32);

    if (half == 0) {
        float v = H[(size_t)d * NC + c] + bias[c] + acc;
        H[(size_t)d * NC + c] = fmaxf(v, 0.f);
    }
}

// ---------------- pool (reads relu'd node values from H root slot) ----------
__global__ __launch_bounds__(256) void pool_kernel(const float* __restrict__ H,
                                                   const int* __restrict__ batch,
                                                   float* __restrict__ pooled) {
    __shared__ float lpool[N_GRAPHS][HID + 1];
    int t = threadIdx.x;
    for (int i = t; i < N_GRAPHS * (HID + 1); i += 256) ((float*)lpool)[i] = 0.f;
    __syncthreads();

    int c = t & 31;
    int nl = t >> 5;
    int n0 = blockIdx.x * 256;
    for (int it = 0; it < 32; it++) {
        int n = n0 + it * 8 + nl;
        if (n < N_NODES) {
            float v = H[(size_t)n * NC + c];
            int g = batch[n];
            atomicAdd(&lpool[g][c], v);
        }
    }
    __syncthreads();
    for (int i = t; i < N_GRAPHS * HID; i += 256) {
        int g = i >> 5, c2 = i & 31;
        float v = lpool[g][c2];
        if (v != 0.f) atomicAdd(&pooled[g * HID + c2], v);
    }
}

// ---------------- final FC ----------
__global__ void fc_kernel(const float* __restrict__ pooled, const float* __restrict__ fc_w,
                          const float* __restrict__ fc_b, float* __restrict__ out) {
    int t = threadIdx.x;
    if (t >= N_GRAPHS * OUT_DIM) return;
    int g = t >> 2, o = t & 3;
    float acc = fc_b[o];
    #pragma unroll
    for (int c = 0; c < HID; c++) acc += pooled[g * HID + c] * fc_w[c * OUT_DIM + o];
    out[t] = acc;
}

extern "C" void kernel_launch(void* const* d_in, const int* in_sizes, int n_in,
                              void* d_out, int out_size, void* d_ws, size_t ws_size,
                              hipStream_t stream) {
    const float* node_x  = (const float*)d_in[0];
    const int*   edge_ix = (const int*)d_in[1];
    const int*   e_attr  = (const int*)d_in[2];
    const int*   batch   = (const int*)d_in[3];
    const float* W_rel   = (const float*)d_in[4];
    const float* W_root  = (const float*)d_in[5];
    const float* bias    = (const float*)d_in[6];
    const float* fc_w    = (const float*)d_in[7];
    const float* fc_b    = (const float*)d_in[8];
    float* out = (float*)d_out;

    char* ws = (char*)d_ws;
    size_t off = 0;
    auto alloc = [&](size_t bytes) {
        char* p = ws + off;
        off += (bytes + 255) & ~(size_t)255;
        return p;
    };
    unsigned short* Wbf = (unsigned short*)alloc((size_t)KPAD * NC * 2);  // 256 KB
    float* H       = (float*)alloc((size_t)N_NODES * NC * 4);       // 102.4 MB
    int*   cnt     = (int*)  alloc((size_t)N_NODES * N_REL * 4);    // 2.8 MB (becomes invcnt)
    int*   deg     = (int*)  alloc((size_t)N_NODES * 4);
    int*   offs    = (int*)  alloc((size_t)N_NODES * 4);
    int*   cursor  = (int*)  alloc((size_t)N_NODES * 4);
    int*   perm    = (int*)  alloc((size_t)N_EDGES * 4);            // 6.4 MB
    int*   bsums   = (int*)  alloc((size_t)SCAN_BLOCKS * 4);
    float* pooled  = (float*)alloc((size_t)N_GRAPHS * HID * 4);
    (void)ws_size; (void)in_sizes; (void)n_in; (void)out_size;

    const int* src = edge_ix;
    const int* dst = edge_ix + N_EDGES;

    hipMemsetAsync(cnt, 0, (size_t)N_NODES * N_REL * 4, stream);
    hipMemsetAsync(pooled, 0, (size_t)N_GRAPHS * HID * 4, stream);

    build_wbf<<<(KPAD * NC + 255) / 256, 256, 0, stream>>>(W_root, W_rel, Wbf);

    gemm_mfma<<<((N_NODES + 127) / 128) * 2, 256, 0, stream>>>(node_x, (const uint4*)Wbf, H);

    count_edges<<<(N_EDGES + 255) / 256, 256, 0, stream>>>(dst, e_attr, cnt);
    make_invcnt_deg<<<(N_NODES + 255) / 256, 256, 0, stream>>>(cnt, deg);

    scan1<<<SCAN_BLOCKS, 256, 0, stream>>>(deg, offs, bsums);
    scan2<<<1, 64, 0, stream>>>(bsums);
    scan3<<<(N_NODES + 255) / 256, 256, 0, stream>>>(offs, bsums, cursor);

    perm_build<<<(N_EDGES + 255) / 256, 256, 0, stream>>>(dst, cursor, perm);

    gather_agg<<<(N_NODES + 3) / 4, 256, 0, stream>>>(src, e_attr, perm, cursor, deg,
                                                      (const float*)cnt, bias, H);

    pool_kernel<<<(N_NODES + 255) / 256, 256, 0, stream>>>(H, batch, pooled);

    fc_kernel<<<1, 64, 0, stream>>>(pooled, fc_w, fc_b, out);
}

// Round 4
// 630.718 us; speedup vs baseline: 3.2004x; 1.1809x over previous
//
#include <hip/hip_runtime.h>

#define N_NODES 100000
#define N_EDGES 1600000
#define IN_DIM 500
#define HID 32
#define N_REL 7
#define OUT_DIM 4
#define N_GRAPHS 16
#define NC 256   // (N_REL + 1) * HID: [root | rel0..rel6]
#define KPAD 512
#define KSTEPS 16

#define SCAN_ITEMS 1024
#define SCAN_BLOCKS ((N_NODES + SCAN_ITEMS - 1) / SCAN_ITEMS)   // 98

typedef __attribute__((ext_vector_type(8))) short bf16x8;
typedef __attribute__((ext_vector_type(4))) float f32x4;

__device__ inline unsigned short f2bf(float f) {
    unsigned u = __float_as_uint(f);
    unsigned r = (u + 0x7FFFu + ((u >> 16) & 1u)) >> 16;
    return (unsigned short)r;
}

// ---------------- build Wbf: bf16 B-matrix in MFMA fragment order ----------
// layout: [(ks*4+q)*256 + n] x 8 bf16, element k = ks*32 + q*8 + j (zero k>=500)
__global__ void build_wbf(const float* __restrict__ W_root,
                          const float* __restrict__ W_rel,
                          unsigned short* __restrict__ Wbf) {
    int idx = blockIdx.x * blockDim.x + threadIdx.x;   // 0 .. KPAD*NC-1
    if (idx >= KPAD * NC) return;
    int kk = idx >> 8;
    int n = idx & 255;
    float v = 0.f;
    if (kk < IN_DIM) {
        if (n < HID) v = W_root[kk * HID + n];
        else {
            int r = (n >> 5) - 1;
            v = W_rel[((size_t)r * IN_DIM + kk) * HID + (n & 31)];
        }
    }
    int ks = kk >> 5, q = (kk >> 3) & 3, j = kk & 7;
    Wbf[(size_t)((((ks << 2) + q) << 8) + n) * 8 + j] = f2bf(v);
}

// ---------------- MFMA GEMM: H[N,256] = bf16(A[N,500]) @ Wbf --------------
// block: 256 threads (4 waves), tile 64 rows x 256 cols.
// Phase 1: stream entire 64x500 fp32 A-tile (row-contiguous, DRAM-friendly),
//          convert to bf16, store whole-K fragment-order in LDS (64 KB).
// Phase 2: barrier-free k-loop; B frags from global (L2-hot), A from LDS.
__global__ __launch_bounds__(256) void gemm_mfma(const float* __restrict__ A,
                                                 const uint4* __restrict__ Wbf,
                                                 float* __restrict__ H) {
    __shared__ uint4 Alds[KSTEPS * 4 * 64];   // 64 KB: entry(ksq,row), XOR-swizzled

    const int tid = threadIdx.x;
    const int wave = tid >> 6, lane = tid & 63;
    const int l16 = lane & 15, q = lane >> 4;
    const int row0 = blockIdx.x * 64;
    const int wn = wave * 64;

    // ---- zero the k>=500 pad region (full planes -> swizzle-agnostic) ----
    if (tid < 64) {
        Alds[(63 << 6) | tid] = make_uint4(0u, 0u, 0u, 0u);          // k 504..511
    } else if (tid < 128) {
        int r = tid - 64;                                            // k 500..503
        *(uint2*)((char*)&Alds[(62 << 6) | r] + 8) = make_uint2(0u, 0u);
    }

    // ---- phase 1: load + convert + fragment-order LDS store ----
    {
        const float4* Ablk4 = (const float4*)(A + (size_t)row0 * IN_DIM);
        int rows = N_NODES - row0; if (rows > 64) rows = 64;
        int maxidx = rows * 125;                 // float4s per row = 125
        for (int idx = tid; idx < 64 * 125; idx += 256) {
            if (idx < maxidx) {
                float4 v = Ablk4[idx];
                int row = idx / 125;
                int k = (idx - row * 125) * 4;   // multiple of 4, < 500
                int ksq = k >> 3;                // ks*4+q
                int j = k & 7;                   // 0 or 4
                int e = (ksq << 6) | ((row ^ ksq) & 63);
                ushort4 b;
                b.x = f2bf(v.x); b.y = f2bf(v.y); b.z = f2bf(v.z); b.w = f2bf(v.w);
                *(ushort4*)((unsigned short*)&Alds[e] + j) = b;
            }
        }
    }
    __syncthreads();

    // ---- phase 2: barrier-free K loop ----
    f32x4 acc[4][4];
    #pragma unroll
    for (int mt = 0; mt < 4; mt++)
        #pragma unroll
        for (int nt = 0; nt < 4; nt++)
            #pragma unroll
            for (int r = 0; r < 4; r++) acc[mt][nt][r] = 0.f;

    for (int ks = 0; ks < KSTEPS; ks++) {
        const int ksq = ks * 4 + q;
        bf16x8 bfr[4], afr[4];
        #pragma unroll
        for (int nt = 0; nt < 4; nt++) {
            uint4 t = Wbf[(size_t)(ksq << 8) + wn + nt * 16 + l16];
            bfr[nt] = *(bf16x8*)&t;
        }
        #pragma unroll
        for (int mt = 0; mt < 4; mt++) {
            int e = (ksq << 6) | (((mt * 16 + l16) ^ ksq) & 63);
            afr[mt] = *(const bf16x8*)&Alds[e];
        }
        #pragma unroll
        for (int mt = 0; mt < 4; mt++)
            #pragma unroll
            for (int nt = 0; nt < 4; nt++)
                acc[mt][nt] = __builtin_amdgcn_mfma_f32_16x16x32_bf16(
                    afr[mt], bfr[nt], acc[mt][nt], 0, 0, 0);
    }

    // ---- store: C/D layout col=lane&15, row=(lane>>4)*4+reg ----
    #pragma unroll
    for (int mt = 0; mt < 4; mt++) {
        int rbase = row0 + mt * 16 + q * 4;
        #pragma unroll
        for (int r = 0; r < 4; r++) {
            int row = rbase + r;
            if (row < N_NODES) {
                float* hp = H + (size_t)row * NC + wn + l16;
                #pragma unroll
                for (int nt = 0; nt < 4; nt++) hp[nt * 16] = acc[mt][nt][r];
            }
        }
    }
}

// ---------------- edge degree count per (dst, rel) ----------------
__global__ void count_edges(const int* __restrict__ dst, const int* __restrict__ attr,
                            int* __restrict__ cnt) {
    int e = blockIdx.x * blockDim.x + threadIdx.x;
    if (e >= N_EDGES) return;
    atomicAdd(&cnt[dst[e] * N_REL + attr[e]], 1);
}

// per node: deg[d] = sum_r cnt; cnt -> float 1/max(cnt,1) in place
__global__ void make_invcnt_deg(int* __restrict__ cnt, int* __restrict__ deg) {
    int d = blockIdx.x * blockDim.x + threadIdx.x;
    if (d >= N_NODES) return;
    int total = 0;
    #pragma unroll
    for (int r = 0; r < N_REL; r++) {
        int c = cnt[d * N_REL + r];
        total += c;
        float v = 1.0f / (float)(c > 1 ? c : 1);
        cnt[d * N_REL + r] = __float_as_int(v);
    }
    deg[d] = total;
}

// ---------------- exclusive scan of deg -> offsets ----------------
__global__ __launch_bounds__(256) void scan1(const int* __restrict__ deg,
                                             int* __restrict__ offs,
                                             int* __restrict__ bsums) {
    __shared__ int ss[256];
    int t = threadIdx.x;
    int base = blockIdx.x * SCAN_ITEMS + t * 4;
    int v[4];
    #pragma unroll
    for (int j = 0; j < 4; j++) {
        int idx = base + j;
        v[j] = idx < N_NODES ? deg[idx] : 0;
    }
    int tsum = v[0] + v[1] + v[2] + v[3];
    ss[t] = tsum;
    __syncthreads();
    for (int off = 1; off < 256; off <<= 1) {
        int x = (t >= off) ? ss[t - off] : 0;
        __syncthreads();
        ss[t] += x;
        __syncthreads();
    }
    int excl = ss[t] - tsum;
    if (t == 255) bsums[blockIdx.x] = ss[255];
    int run = excl;
    #pragma unroll
    for (int j = 0; j < 4; j++) {
        int idx = base + j;
        if (idx < N_NODES) offs[idx] = run;
        run += v[j];
    }
}

__global__ void scan2(int* __restrict__ bsums) {
    if (threadIdx.x == 0 && blockIdx.x == 0) {
        int run = 0;
        for (int i = 0; i < SCAN_BLOCKS; i++) {
            int v = bsums[i];
            bsums[i] = run;
            run += v;
        }
    }
}

__global__ void scan3(int* __restrict__ offs, const int* __restrict__ bsums,
                      int* __restrict__ cursor) {
    int i = blockIdx.x * blockDim.x + threadIdx.x;
    if (i >= N_NODES) return;
    int v = offs[i] + bsums[i >> 10];
    offs[i] = v;
    cursor[i] = v;
}

// ---------------- build dst-sorted packed edge records: (src<<3)|rel --------
__global__ void rec_build(const int* __restrict__ src, const int* __restrict__ dst,
                          const int* __restrict__ attr, int* __restrict__ cursor,
                          int* __restrict__ rec) {
    int e = blockIdx.x * blockDim.x + threadIdx.x;
    if (e >= N_EDGES) return;
    int p = atomicAdd(&cursor[dst[e]], 1);
    rec[p] = (src[e] << 3) | attr[e];
}

// ---------------- gather aggregation: one HALF-wave (32 lanes) per node ----
// 8x unrolled: 8 independent H-gather loads in flight per half-wave
__global__ __launch_bounds__(256) void gather_agg(const int* __restrict__ rec,
                                                  const int* __restrict__ cursor,
                                                  const int* __restrict__ deg,
                                                  const float* __restrict__ invcnt,
                                                  const float* __restrict__ bias,
                                                  float* __restrict__ H) {
    int d = blockIdx.x * 8 + (threadIdx.x >> 5);
    if (d >= N_NODES) return;
    int c = threadIdx.x & 31;

    int dg = deg[d];
    int end = cursor[d];          // cursor[d] == offs[d] + deg[d] after rec_build
    int start = end - dg;

    float acc = 0.f;
    int i = start;
    for (; i + 7 < end; i += 8) {
        int q0 = rec[i], q1 = rec[i + 1], q2 = rec[i + 2], q3 = rec[i + 3];
        int q4 = rec[i + 4], q5 = rec[i + 5], q6 = rec[i + 6], q7 = rec[i + 7];
        float h0 = H[(size_t)(q0 >> 3) * NC + ((q0 & 7) + 1) * HID + c];
        float h1 = H[(size_t)(q1 >> 3) * NC + ((q1 & 7) + 1) * HID + c];
        float h2 = H[(size_t)(q2 >> 3) * NC + ((q2 & 7) + 1) * HID + c];
        float h3 = H[(size_t)(q3 >> 3) * NC + ((q3 & 7) + 1) * HID + c];
        float h4 = H[(size_t)(q4 >> 3) * NC + ((q4 & 7) + 1) * HID + c];
        float h5 = H[(size_t)(q5 >> 3) * NC + ((q5 & 7) + 1) * HID + c];
        float h6 = H[(size_t)(q6 >> 3) * NC + ((q6 & 7) + 1) * HID + c];
        float h7 = H[(size_t)(q7 >> 3) * NC + ((q7 & 7) + 1) * HID + c];
        acc = fmaf(h0, invcnt[d * N_REL + (q0 & 7)], acc);
        acc = fmaf(h1, invcnt[d * N_REL + (q1 & 7)], acc);
        acc = fmaf(h2, invcnt[d * N_REL + (q2 & 7)], acc);
        acc = fmaf(h3, invcnt[d * N_REL + (q3 & 7)], acc);
        acc = fmaf(h4, invcnt[d * N_REL + (q4 & 7)], acc);
        acc = fmaf(h5, invcnt[d * N_REL + (q5 & 7)], acc);
        acc = fmaf(h6, invcnt[d * N_REL + (q6 & 7)], acc);
        acc = fmaf(h7, invcnt[d * N_REL + (q7 & 7)], acc);
    }
    for (; i < end; i++) {
        int qq = rec[i];
        acc = fmaf(H[(size_t)(qq >> 3) * NC + ((qq & 7) + 1) * HID + c],
                   invcnt[d * N_REL + (qq & 7)], acc);
    }

    float v = H[(size_t)d * NC + c] + bias[c] + acc;
    H[(size_t)d * NC + c] = fmaxf(v, 0.f);
}

// ---------------- pool (reads relu'd node values from H root slot) ----------
__global__ __launch_bounds__(256) void pool_kernel(const float* __restrict__ H,
                                                   const int* __restrict__ batch,
                                                   float* __restrict__ pooled) {
    __shared__ float lpool[N_GRAPHS][HID + 1];
    int t = threadIdx.x;
    for (int i = t; i < N_GRAPHS * (HID + 1); i += 256) ((float*)lpool)[i] = 0.f;
    __syncthreads();

    int c = t & 31;
    int nl = t >> 5;
    int n0 = blockIdx.x * 256;
    for (int it = 0; it < 32; it++) {
        int n = n0 + it * 8 + nl;
        if (n < N_NODES) {
            float v = H[(size_t)n * NC + c];
            int g = batch[n];
            atomicAdd(&lpool[g][c], v);
        }
    }
    __syncthreads();
    for (int i = t; i < N_GRAPHS * HID; i += 256) {
        int g = i >> 5, c2 = i & 31;
        float v = lpool[g][c2];
        if (v != 0.f) atomicAdd(&pooled[g * HID + c2], v);
    }
}

// ---------------- final FC ----------
__global__ void fc_kernel(const float* __restrict__ pooled, const float* __restrict__ fc_w,
                          const float* __restrict__ fc_b, float* __restrict__ out) {
    int t = threadIdx.x;
    if (t >= N_GRAPHS * OUT_DIM) return;
    int g = t >> 2, o = t & 3;
    float acc = fc_b[o];
    #pragma unroll
    for (int c = 0; c < HID; c++) acc += pooled[g * HID + c] * fc_w[c * OUT_DIM + o];
    out[t] = acc;
}

extern "C" void kernel_launch(void* const* d_in, const int* in_sizes, int n_in,
                              void* d_out, int out_size, void* d_ws, size_t ws_size,
                              hipStream_t stream) {
    const float* node_x  = (const float*)d_in[0];
    const int*   edge_ix = (const int*)d_in[1];
    const int*   e_attr  = (const int*)d_in[2];
    const int*   batch   = (const int*)d_in[3];
    const float* W_rel   = (const float*)d_in[4];
    const float* W_root  = (const float*)d_in[5];
    const float* bias    = (const float*)d_in[6];
    const float* fc_w    = (const float*)d_in[7];
    const float* fc_b    = (const float*)d_in[8];
    float* out = (float*)d_out;

    char* ws = (char*)d_ws;
    size_t off = 0;
    auto alloc = [&](size_t bytes) {
        char* p = ws + off;
        off += (bytes + 255) & ~(size_t)255;
        return p;
    };
    unsigned short* Wbf = (unsigned short*)alloc((size_t)KPAD * NC * 2);  // 256 KB
    float* H       = (float*)alloc((size_t)N_NODES * NC * 4);       // 102.4 MB
    int*   cnt     = (int*)  alloc((size_t)N_NODES * N_REL * 4);    // 2.8 MB (becomes invcnt)
    int*   deg     = (int*)  alloc((size_t)N_NODES * 4);
    int*   offs    = (int*)  alloc((size_t)N_NODES * 4);
    int*   cursor  = (int*)  alloc((size_t)N_NODES * 4);
    int*   rec     = (int*)  alloc((size_t)N_EDGES * 4);            // 6.4 MB
    int*   bsums   = (int*)  alloc((size_t)SCAN_BLOCKS * 4);
    float* pooled  = (float*)alloc((size_t)N_GRAPHS * HID * 4);
    (void)ws_size; (void)in_sizes; (void)n_in; (void)out_size;

    const int* src = edge_ix;
    const int* dst = edge_ix + N_EDGES;

    hipMemsetAsync(cnt, 0, (size_t)N_NODES * N_REL * 4, stream);
    hipMemsetAsync(pooled, 0, (size_t)N_GRAPHS * HID * 4, stream);

    build_wbf<<<(KPAD * NC + 255) / 256, 256, 0, stream>>>(W_root, W_rel, Wbf);

    gemm_mfma<<<(N_NODES + 63) / 64, 256, 0, stream>>>(node_x, (const uint4*)Wbf, H);

    count_edges<<<(N_EDGES + 255) / 256, 256, 0, stream>>>(dst, e_attr, cnt);
    make_invcnt_deg<<<(N_NODES + 255) / 256, 256, 0, stream>>>(cnt, deg);

    scan1<<<SCAN_BLOCKS, 256, 0, stream>>>(deg, offs, bsums);
    scan2<<<1, 64, 0, stream>>>(bsums);
    scan3<<<(N_NODES + 255) / 256, 256, 0, stream>>>(offs, bsums, cursor);

    rec_build<<<(N_EDGES + 255) / 256, 256, 0, stream>>>(src, dst, e_attr, cursor, rec);

    gather_agg<<<(N_NODES + 7) / 8, 256, 0, stream>>>(rec, cursor, deg,
                                                      (const float*)cnt, bias, H);

    pool_kernel<<<(N_NODES + 255) / 256, 256, 0, stream>>>(H, batch, pooled);

    fc_kernel<<<1, 64, 0, stream>>>(pooled, fc_w, fc_b, out);
}

// Round 5
// 602.603 us; speedup vs baseline: 3.3497x; 1.0467x over previous
//
#include <hip/hip_runtime.h>

#define N_NODES 100000
#define N_EDGES 1600000
#define IN_DIM 500
#define HID 32
#define N_REL 7
#define OUT_DIM 4
#define N_GRAPHS 16
#define NC 256      // (N_REL + 1) * HID: [root | rel0..rel6]
#define MC 224      // message cols (N_REL * HID)
#define KPAD 512

#define SCAN_ITEMS 1024
#define SCAN_BLOCKS ((N_NODES + SCAN_ITEMS - 1) / SCAN_ITEMS)   // 98

typedef __attribute__((ext_vector_type(8))) short bf16x8;
typedef __attribute__((ext_vector_type(4))) float f32x4;

__device__ inline unsigned short f2bf(float f) {
    unsigned u = __float_as_uint(f);
    unsigned r = (u + 0x7FFFu + ((u >> 16) & 1u)) >> 16;
    return (unsigned short)r;
}
__device__ inline float bf2f(unsigned short b) {
    return __uint_as_float((unsigned)b << 16);
}

// ---------------- build Wbf: bf16 B-matrix in MFMA fragment order ----------
// layout: [(ks*4+q)*256 + n] x 8 bf16, element k = ks*32 + q*8 + j (zero k>=500)
__global__ void build_wbf(const float* __restrict__ W_root,
                          const float* __restrict__ W_rel,
                          unsigned short* __restrict__ Wbf) {
    int idx = blockIdx.x * blockDim.x + threadIdx.x;   // 0 .. KPAD*NC-1
    if (idx >= KPAD * NC) return;
    int kk = idx >> 8;
    int n = idx & 255;
    float v = 0.f;
    if (kk < IN_DIM) {
        if (n < HID) v = W_root[kk * HID + n];
        else {
            int r = (n >> 5) - 1;
            v = W_rel[((size_t)r * IN_DIM + kk) * HID + (n & 31)];
        }
    }
    int ks = kk >> 5, q = (kk >> 3) & 3, j = kk & 7;
    Wbf[(size_t)((((ks << 2) + q) << 8) + n) * 8 + j] = f2bf(v);
}

// ---------------- MFMA GEMM: [Hr fp32 | Hm bf16] = bf16(A) @ Wbf ----------
// block: 256 threads (4 waves), tile 64 rows x 256 cols.
// K split in two 32KB-LDS halves -> 4 blocks/CU for stage/compute overlap.
__global__ __launch_bounds__(256, 4) void gemm_mfma(const float* __restrict__ A,
                                                    const uint4* __restrict__ Wbf,
                                                    float* __restrict__ Hr,
                                                    unsigned short* __restrict__ Hm) {
    __shared__ uint4 Alds[32 * 64];   // 32 KB: entry(ksq_local, row^swz)

    const int tid = threadIdx.x;
    const int wave = tid >> 6, lane = tid & 63;
    const int l16 = lane & 15, q = lane >> 4;
    const int row0 = blockIdx.x * 64;
    const int wn = wave * 64;

    int rows_valid = N_NODES - row0; if (rows_valid > 64) rows_valid = 64;
    const float4* Ablk4 = (const float4*)(A + (size_t)row0 * IN_DIM);

    f32x4 acc[4][4];
    #pragma unroll
    for (int mt = 0; mt < 4; mt++)
        #pragma unroll
        for (int nt = 0; nt < 4; nt++)
            #pragma unroll
            for (int r = 0; r < 4; r++) acc[mt][nt][r] = 0.f;

    for (int half = 0; half < 2; half++) {
        if (half) __syncthreads();   // prev compute done before LDS overwrite
        // ---- stage: 64 rows x 256 k (one full row per wave per iter) ----
        #pragma unroll 4
        for (int it = 0; it < 16; it++) {
            int idx = it * 256 + tid;
            int row = idx >> 6, slot = idx & 63;
            int k = half * 256 + slot * 4;
            float4 v = make_float4(0.f, 0.f, 0.f, 0.f);
            if (row < rows_valid && k < IN_DIM)
                v = Ablk4[row * 125 + (k >> 2)];
            int ksq = slot >> 1;                       // local 0..31
            int e = (ksq << 6) | ((row ^ ksq) & 63);
            ushort4 b;
            b.x = f2bf(v.x); b.y = f2bf(v.y); b.z = f2bf(v.z); b.w = f2bf(v.w);
            *(ushort4*)((unsigned short*)&Alds[e] + (slot & 1) * 4) = b;
        }
        __syncthreads();
        // ---- compute 8 k-steps ----
        #pragma unroll 2
        for (int ksl = 0; ksl < 8; ksl++) {
            int ksq_l = ksl * 4 + q;
            int ksq_g = half * 32 + ksq_l;
            bf16x8 bfr[4], afr[4];
            #pragma unroll
            for (int nt = 0; nt < 4; nt++) {
                uint4 t = Wbf[(size_t)(ksq_g << 8) + wn + nt * 16 + l16];
                bfr[nt] = *(bf16x8*)&t;
            }
            #pragma unroll
            for (int mt = 0; mt < 4; mt++)
                afr[mt] = *(const bf16x8*)&Alds[(ksq_l << 6) | (((mt * 16 + l16) ^ ksq_l) & 63)];
            #pragma unroll
            for (int mt = 0; mt < 4; mt++)
                #pragma unroll
                for (int nt = 0; nt < 4; nt++)
                    acc[mt][nt] = __builtin_amdgcn_mfma_f32_16x16x32_bf16(
                        afr[mt], bfr[nt], acc[mt][nt], 0, 0, 0);
        }
    }

    // ---- store: C/D layout col=lane&15, row=(lane>>4)*4+reg ----
    #pragma unroll
    for (int mt = 0; mt < 4; mt++) {
        int rbase = row0 + mt * 16 + q * 4;
        #pragma unroll
        for (int r = 0; r < 4; r++) {
            int row = rbase + r;
            if (row < N_NODES) {
                #pragma unroll
                for (int nt = 0; nt < 4; nt++) {
                    int col = wn + nt * 16 + l16;
                    float v = acc[mt][nt][r];
                    if (wave == 0 && nt < 2)            // col < 32: root slice
                        Hr[(size_t)row * HID + col] = v;
                    else
                        Hm[(size_t)row * MC + (col - HID)] = f2bf(v);
                }
            }
        }
    }
}

// ---------------- edge degree count per (dst, rel) ----------------
__global__ void count_edges(const int* __restrict__ dst, const int* __restrict__ attr,
                            int* __restrict__ cnt) {
    int e = blockIdx.x * blockDim.x + threadIdx.x;
    if (e >= N_EDGES) return;
    atomicAdd(&cnt[dst[e] * N_REL + attr[e]], 1);
}

// ---------------- fused: invcnt + deg + block scan ----------------
__global__ __launch_bounds__(256) void scan1(int* __restrict__ cnt,
                                             int* __restrict__ deg,
                                             int* __restrict__ offs,
                                             int* __restrict__ bsums) {
    __shared__ int ss[256];
    int t = threadIdx.x;
    int base = blockIdx.x * SCAN_ITEMS + t * 4;
    int v[4];
    #pragma unroll
    for (int j = 0; j < 4; j++) {
        int idx = base + j;
        int total = 0;
        if (idx < N_NODES) {
            #pragma unroll
            for (int r = 0; r < N_REL; r++) {
                int c = cnt[idx * N_REL + r];
                total += c;
                float iv = 1.0f / (float)(c > 1 ? c : 1);
                cnt[idx * N_REL + r] = __float_as_int(iv);
            }
            deg[idx] = total;
        }
        v[j] = total;
    }
    int tsum = v[0] + v[1] + v[2] + v[3];
    ss[t] = tsum;
    __syncthreads();
    for (int off = 1; off < 256; off <<= 1) {
        int x = (t >= off) ? ss[t - off] : 0;
        __syncthreads();
        ss[t] += x;
        __syncthreads();
    }
    int excl = ss[t] - tsum;
    if (t == 255) bsums[blockIdx.x] = ss[255];
    int run = excl;
    #pragma unroll
    for (int j = 0; j < 4; j++) {
        int idx = base + j;
        if (idx < N_NODES) offs[idx] = run;
        run += v[j];
    }
}

__global__ void scan2(int* __restrict__ bsums) {
    if (threadIdx.x == 0 && blockIdx.x == 0) {
        int run = 0;
        for (int i = 0; i < SCAN_BLOCKS; i++) {
            int v = bsums[i];
            bsums[i] = run;
            run += v;
        }
    }
}

__global__ void scan3(int* __restrict__ offs, const int* __restrict__ bsums,
                      int* __restrict__ cursor) {
    int i = blockIdx.x * blockDim.x + threadIdx.x;
    if (i >= N_NODES) return;
    int v = offs[i] + bsums[i >> 10];
    offs[i] = v;
    cursor[i] = v;
}

// ---------------- build dst-sorted packed edge records: (src<<3)|rel --------
__global__ void rec_build(const int* __restrict__ src, const int* __restrict__ dst,
                          const int* __restrict__ attr, int* __restrict__ cursor,
                          int* __restrict__ rec) {
    int e = blockIdx.x * blockDim.x + threadIdx.x;
    if (e >= N_EDGES) return;
    int p = atomicAdd(&cursor[dst[e]], 1);
    rec[p] = (src[e] << 3) | attr[e];
}

// ---------------- gather aggregation: one HALF-wave (32 lanes) per node ----
// bf16 messages: 64 B random traffic per edge; 8 loads in flight
__global__ __launch_bounds__(256) void gather_agg(const int* __restrict__ rec,
                                                  const int* __restrict__ cursor,
                                                  const int* __restrict__ deg,
                                                  const float* __restrict__ invcnt,
                                                  const float* __restrict__ bias,
                                                  const unsigned short* __restrict__ Hm,
                                                  float* __restrict__ Hr) {
    int d = blockIdx.x * 8 + (threadIdx.x >> 5);
    if (d >= N_NODES) return;
    int c = threadIdx.x & 31;

    int dg = deg[d];
    int end = cursor[d];          // cursor[d] == offs[d] + deg[d] after rec_build
    int start = end - dg;

    float acc = 0.f;
    int i = start;
    for (; i + 7 < end; i += 8) {
        int q0 = rec[i], q1 = rec[i + 1], q2 = rec[i + 2], q3 = rec[i + 3];
        int q4 = rec[i + 4], q5 = rec[i + 5], q6 = rec[i + 6], q7 = rec[i + 7];
        float h0 = bf2f(Hm[(size_t)(q0 >> 3) * MC + (q0 & 7) * HID + c]);
        float h1 = bf2f(Hm[(size_t)(q1 >> 3) * MC + (q1 & 7) * HID + c]);
        float h2 = bf2f(Hm[(size_t)(q2 >> 3) * MC + (q2 & 7) * HID + c]);
        float h3 = bf2f(Hm[(size_t)(q3 >> 3) * MC + (q3 & 7) * HID + c]);
        float h4 = bf2f(Hm[(size_t)(q4 >> 3) * MC + (q4 & 7) * HID + c]);
        float h5 = bf2f(Hm[(size_t)(q5 >> 3) * MC + (q5 & 7) * HID + c]);
        float h6 = bf2f(Hm[(size_t)(q6 >> 3) * MC + (q6 & 7) * HID + c]);
        float h7 = bf2f(Hm[(size_t)(q7 >> 3) * MC + (q7 & 7) * HID + c]);
        acc = fmaf(h0, invcnt[d * N_REL + (q0 & 7)], acc);
        acc = fmaf(h1, invcnt[d * N_REL + (q1 & 7)], acc);
        acc = fmaf(h2, invcnt[d * N_REL + (q2 & 7)], acc);
        acc = fmaf(h3, invcnt[d * N_REL + (q3 & 7)], acc);
        acc = fmaf(h4, invcnt[d * N_REL + (q4 & 7)], acc);
        acc = fmaf(h5, invcnt[d * N_REL + (q5 & 7)], acc);
        acc = fmaf(h6, invcnt[d * N_REL + (q6 & 7)], acc);
        acc = fmaf(h7, invcnt[d * N_REL + (q7 & 7)], acc);
    }
    for (; i < end; i++) {
        int qq = rec[i];
        acc = fmaf(bf2f(Hm[(size_t)(qq >> 3) * MC + (qq & 7) * HID + c]),
                   invcnt[d * N_REL + (qq & 7)], acc);
    }

    float v = Hr[(size_t)d * HID + c] + bias[c] + acc;
    Hr[(size_t)d * HID + c] = fmaxf(v, 0.f);
}

// ---------------- pool (contiguous Hr read) ----------
__global__ __launch_bounds__(256) void pool_kernel(const float* __restrict__ Hr,
                                                   const int* __restrict__ batch,
                                                   float* __restrict__ pooled) {
    __shared__ float lpool[N_GRAPHS][HID + 1];
    int t = threadIdx.x;
    for (int i = t; i < N_GRAPHS * (HID + 1); i += 256) ((float*)lpool)[i] = 0.f;
    __syncthreads();

    int c = t & 31;
    int nl = t >> 5;
    int n0 = blockIdx.x * 256;
    for (int it = 0; it < 32; it++) {
        int n = n0 + it * 8 + nl;
        if (n < N_NODES) {
            float v = Hr[(size_t)n * HID + c];
            int g = batch[n];
            atomicAdd(&lpool[g][c], v);
        }
    }
    __syncthreads();
    for (int i = t; i < N_GRAPHS * HID; i += 256) {
        int g = i >> 5, c2 = i & 31;
        float v = lpool[g][c2];
        if (v != 0.f) atomicAdd(&pooled[g * HID + c2], v);
    }
}

// ---------------- final FC ----------
__global__ void fc_kernel(const float* __restrict__ pooled, const float* __restrict__ fc_w,
                          const float* __restrict__ fc_b, float* __restrict__ out) {
    int t = threadIdx.x;
    if (t >= N_GRAPHS * OUT_DIM) return;
    int g = t >> 2, o = t & 3;
    float acc = fc_b[o];
    #pragma unroll
    for (int c = 0; c < HID; c++) acc += pooled[g * HID + c] * fc_w[c * OUT_DIM + o];
    out[t] = acc;
}

extern "C" void kernel_launch(void* const* d_in, const int* in_sizes, int n_in,
                              void* d_out, int out_size, void* d_ws, size_t ws_size,
                              hipStream_t stream) {
    const float* node_x  = (const float*)d_in[0];
    const int*   edge_ix = (const int*)d_in[1];
    const int*   e_attr  = (const int*)d_in[2];
    const int*   batch   = (const int*)d_in[3];
    const float* W_rel   = (const float*)d_in[4];
    const float* W_root  = (const float*)d_in[5];
    const float* bias    = (const float*)d_in[6];
    const float* fc_w    = (const float*)d_in[7];
    const float* fc_b    = (const float*)d_in[8];
    float* out = (float*)d_out;

    char* ws = (char*)d_ws;
    size_t off = 0;
    auto alloc = [&](size_t bytes) {
        char* p = ws + off;
        off += (bytes + 255) & ~(size_t)255;
        return p;
    };
    unsigned short* Wbf = (unsigned short*)alloc((size_t)KPAD * NC * 2);  // 256 KB
    float* Hr      = (float*)alloc((size_t)N_NODES * HID * 4);            // 12.8 MB
    unsigned short* Hm = (unsigned short*)alloc((size_t)N_NODES * MC * 2);// 44.8 MB
    int*   cnt     = (int*)  alloc((size_t)N_NODES * N_REL * 4);          // 2.8 MB (becomes invcnt)
    int*   deg     = (int*)  alloc((size_t)N_NODES * 4);
    int*   offs    = (int*)  alloc((size_t)N_NODES * 4);
    int*   cursor  = (int*)  alloc((size_t)N_NODES * 4);
    int*   rec     = (int*)  alloc((size_t)N_EDGES * 4);                  // 6.4 MB
    int*   bsums   = (int*)  alloc((size_t)SCAN_BLOCKS * 4);
    float* pooled  = (float*)alloc((size_t)N_GRAPHS * HID * 4);
    (void)ws_size; (void)in_sizes; (void)n_in; (void)out_size;

    const int* src = edge_ix;
    const int* dst = edge_ix + N_EDGES;

    hipMemsetAsync(cnt, 0, (size_t)N_NODES * N_REL * 4, stream);
    hipMemsetAsync(pooled, 0, (size_t)N_GRAPHS * HID * 4, stream);

    build_wbf<<<(KPAD * NC + 255) / 256, 256, 0, stream>>>(W_root, W_rel, Wbf);

    gemm_mfma<<<(N_NODES + 63) / 64, 256, 0, stream>>>(node_x, (const uint4*)Wbf, Hr, Hm);

    count_edges<<<(N_EDGES + 255) / 256, 256, 0, stream>>>(dst, e_attr, cnt);

    scan1<<<SCAN_BLOCKS, 256, 0, stream>>>(cnt, deg, offs, bsums);
    scan2<<<1, 64, 0, stream>>>(bsums);
    scan3<<<(N_NODES + 255) / 256, 256, 0, stream>>>(offs, bsums, cursor);

    rec_build<<<(N_EDGES + 255) / 256, 256, 0, stream>>>(src, dst, e_attr, cursor, rec);

    gather_agg<<<(N_NODES + 7) / 8, 256, 0, stream>>>(rec, cursor, deg,
                                                      (const float*)cnt, bias, Hm, Hr);

    pool_kernel<<<(N_NODES + 255) / 256, 256, 0, stream>>>(Hr, batch, pooled);

    fc_kernel<<<1, 64, 0, stream>>>(pooled, fc_w, fc_b, out);
}